// Round 12
// baseline (188.386 us; speedup 1.0000x reference)
//
#include <hip/hip_runtime.h>
#include <math.h>

#define GRID_N 5
#define LOG2E 1.4426950408889634f
#define EXP2F __builtin_amdgcn_exp2f
#define BATCH 2048

__device__ __forceinline__ float tanh_fast(float v) {   // NaN-safe, saturating
    float e = EXP2F(2.0f * LOG2E * v);
    return 1.0f - 2.0f / (e + 1.0f);
}

// Per-(i,o) bin tables:  K = -s*log2e
//   A[k] = sum_{g_idx < k} w_g * 2^{-K*g},  B[k] = sum_{g_idx >= k} w_g * 2^{+K*g}
// T[i][k][o][2] = {A,B} (k=0..5);  Kt[i][o] = K
__device__ __forceinline__ void prep_one(const float* __restrict__ w,
                                         const float* __restrict__ s,
                                         float* __restrict__ T, float* __restrict__ Kt,
                                         int O, int I, int idx) {
    int o = idx / I, i = idx % I;               // w,s are [O][I(][G)]
    float K = -s[idx] * LOG2E;
    const float gv[5] = {-1.f, -0.5f, 0.f, 0.5f, 1.f};
    float A[6], B[6];
    A[0] = 0.f; B[5] = 0.f;
#pragma unroll
    for (int g = 0; g < 5; g++)
        A[g + 1] = A[g] + w[idx * GRID_N + g] * EXP2F(-K * gv[g]);
#pragma unroll
    for (int g = 4; g >= 0; g--)
        B[g] = B[g + 1] + w[idx * GRID_N + g] * EXP2F(K * gv[g]);
#pragma unroll
    for (int k = 0; k < 6; k++) {
        T[((i * 6 + k) * O + o) * 2 + 0] = A[k];
        T[((i * 6 + k) * O + o) * 2 + 1] = B[k];
    }
    Kt[i * O + o] = K;
}

// tables for all 3 layers + xn0 = tanh(x)
__global__ __launch_bounds__(256) void prep_all(
    const float* __restrict__ x,  float* __restrict__ xn0,
    const float* __restrict__ w1, const float* __restrict__ s1, float* T1, float* K1,
    const float* __restrict__ w2, const float* __restrict__ s2, float* T2, float* K2,
    const float* __restrict__ w3, const float* __restrict__ s3, float* T3, float* K3) {
    int idx = blockIdx.x * 256 + threadIdx.x;
    if (idx < 262144) { xn0[idx] = tanh_fast(x[idx]); return; }
    idx -= 262144;
    if (idx < 32768)       prep_one(w1, s1, T1, K1, 256, 128, idx);
    else if (idx < 65536)  prep_one(w2, s2, T2, K2, 128, 256, idx - 32768);
    else if (idx < 73728)  prep_one(w3, s3, T3, K3,  64, 128, idx - 65536);
}

// ---- kan_tile: LDS table tiles amortized over a b-range ----
// out[b,o] (+)= sum_i A[i,bin,o]*2^{K*xn} + B[i,bin,o]*2^{-K*xn}
// Block = (oc, b-range of 16) = 4 waves x 4 b's. Loop over 8-i tiles:
//   barrier; ds_write tile t (from regs); issue global loads tile t+1 -> regs;
//   barrier; compute 4b x 8i per wave from LDS.
// Tile = [8i][6k][64o]{A,B} 24 KB + K [8i][64o] 2 KB. Stage re-read from L2 is
// per-BLOCK (not per-term): ~200 MB/layer total. Inner term: 1 ds_read_b64
// (bin wave-uniform -> contiguous 512B, conflict-free) + mul + 2 exp2 + 2 fma.
// bin computed on SALU from scalarized xn via monotone int key.
// EPI: 0 = write tanh(relu(acc)) (pre-tanh'd for next layer); 1 = raw partial.
template<int IN, int OUT, int OCH, int HALVES, int BPT, int EPI>
__global__ __launch_bounds__(256) void kan_tile(
    const float* __restrict__ xn,    // [B][IN*HALVES] ALREADY tanh'd
    const char*  __restrict__ Tb,    // [IN*HALVES][6][OUT]{A,B} f32 bytes
    const char*  __restrict__ Kb,    // [IN*HALVES][OUT] f32 bytes
    float* __restrict__ outp)        // [HALVES][B][OUT]
{
    constexpr int NIB  = IN / 8;                 // tiles
    constexpr int BR   = 4 * BPT;                // b-rows per block
    constexpr int XSTR = IN * HALVES;
    __shared__ float4 ldsv[26624 / 16];          // 24 KB AB + 2 KB K
    char* lds = (char*)ldsv;

    const int tid  = threadIdx.x;
    const int lane = tid & 63;
    const int w    = tid >> 6;
    const int h    = (HALVES > 1) ? (int)(blockIdx.x % HALVES) : 0;
    const int q    = blockIdx.x / HALVES;
    const int oc   = q % OCH;
    const int bb   = q / OCH;
    const int o    = (oc << 6) | lane;
    const int bw   = __builtin_amdgcn_readfirstlane(bb * BR + w * BPT);

    const char*  Tbase = Tb + (size_t)h * IN * 6 * OUT * 8 + ((size_t)oc << 9);
    const char*  Kbase = Kb + (size_t)h * IN * OUT * 4 + ((size_t)oc << 8);
    const float* xb    = xn + h * IN;
    float*       op    = outp + (size_t)h * BATCH * OUT;

    float acc[BPT];
#pragma unroll
    for (int j = 0; j < BPT; j++) acc[j] = 0.f;

    float4 sreg[6];
    float2 kreg;

    // prologue: load tile 0 into regs
#pragma unroll
    for (int n = 0; n < 6; n++) {
        int e = n * 256 + tid;
        sreg[n] = *(const float4*)(Tbase + (size_t)(e >> 5) * (OUT * 8) + ((e & 31) << 4));
    }
    kreg = *(const float2*)(Kbase + (size_t)(tid >> 5) * (OUT * 4) + ((tid & 31) << 3));

#pragma unroll 1
    for (int t = 0; t < NIB; t++) {
        __syncthreads();                         // prev compute done reading LDS
        // commit tile t to LDS
#pragma unroll
        for (int n = 0; n < 6; n++)
            *(float4*)(lds + ((n * 256 + tid) << 4)) = sreg[n];
        *(float2*)(lds + 24576 + (tid << 3)) = kreg;
        // prefetch tile t+1 -> regs (latency hides under compute below)
        if (t + 1 < NIB) {
#pragma unroll
            for (int n = 0; n < 6; n++) {
                int e = n * 256 + tid;
                sreg[n] = *(const float4*)(Tbase + (size_t)((t + 1) * 48 + (e >> 5)) * (OUT * 8)
                                            + ((e & 31) << 4));
            }
            kreg = *(const float2*)(Kbase + (size_t)((t + 1) * 8 + (tid >> 5)) * (OUT * 4)
                                     + ((tid & 31) << 3));
        }
        __syncthreads();                         // tile t visible

        // scalarize xn + bins for this tile (SGPR-resident, SALU bin chain)
        int xbits[BPT][8];
#pragma unroll
        for (int j = 0; j < BPT; j++) {
            const float* xr = xb + (size_t)(bw + j) * XSTR + t * 8;
            float4 xa = *(const float4*)(xr);
            float4 xc = *(const float4*)(xr + 4);
            xbits[j][0] = __builtin_amdgcn_readfirstlane(__float_as_int(xa.x));
            xbits[j][1] = __builtin_amdgcn_readfirstlane(__float_as_int(xa.y));
            xbits[j][2] = __builtin_amdgcn_readfirstlane(__float_as_int(xa.z));
            xbits[j][3] = __builtin_amdgcn_readfirstlane(__float_as_int(xa.w));
            xbits[j][4] = __builtin_amdgcn_readfirstlane(__float_as_int(xc.x));
            xbits[j][5] = __builtin_amdgcn_readfirstlane(__float_as_int(xc.y));
            xbits[j][6] = __builtin_amdgcn_readfirstlane(__float_as_int(xc.z));
            xbits[j][7] = __builtin_amdgcn_readfirstlane(__float_as_int(xc.w));
        }

#pragma unroll
        for (int u = 0; u < 8; u++) {
            float Kv = *(const float*)(lds + 24576 + u * 256 + (lane << 2));
#pragma unroll
            for (int j = 0; j < BPT; j++) {
                int bits = xbits[j][u];
                int key  = bits ^ ((bits >> 31) & 0x7fffffff);   // monotone f32 key
                int k    = 1 + (key >= (int)0xC0FFFFFF)          // xn >= -0.5
                             + (key >= 0)                        // xn >=  0
                             + (key >= 0x3F000000)               // xn >=  0.5
                             + (key >= 0x3F800000);              // xn >=  1.0
                float2 ab = *(const float2*)(lds + u * 3072 + (k << 9) + (lane << 3));
                float tt  = Kv * __int_as_float(bits);
                acc[j] += ab.x * EXP2F(tt) + ab.y * EXP2F(-tt);
            }
        }
    }

#pragma unroll
    for (int j = 0; j < BPT; j++) {
        float z = acc[j];
        if (EPI == 0) z = tanh_fast(fmaxf(z, 0.f));   // pre-tanh for next layer
        op[(size_t)(bw + j) * OUT + o] = z;
    }
}

// h2[e] = tanh(relu(p0[e]+p1[e]))
__global__ __launch_bounds__(256) void combine_tanh(
    const float* __restrict__ p, float* __restrict__ out, int n) {
    int e = blockIdx.x * 256 + threadIdx.x;
    if (e >= n) return;
    out[e] = tanh_fast(fmaxf(p[e] + p[n + e], 0.f));
}

// out[e] = sigmoid(p0[e] + p1[e])
__global__ __launch_bounds__(256) void sigmoid_combine(
    const float* __restrict__ p, float* __restrict__ out, int n) {
    int e = blockIdx.x * 256 + threadIdx.x;
    if (e >= n) return;
    float z = p[e] + p[n + e];
    out[e] = 1.0f / (1.0f + EXP2F(-LOG2E * z));
}

extern "C" void kernel_launch(void* const* d_in, const int* in_sizes, int n_in,
                              void* d_out, int out_size, void* d_ws, size_t ws_size,
                              hipStream_t stream) {
    const float* x  = (const float*)d_in[0];
    const float* w1 = (const float*)d_in[1];
    const float* s1 = (const float*)d_in[2];
    const float* w2 = (const float*)d_in[3];
    const float* s2 = (const float*)d_in[4];
    const float* w3 = (const float*)d_in[5];
    const float* s3 = (const float*)d_in[6];
    float* out = (float*)d_out;

    float* ws  = (float*)d_ws;
    float* xn0 = ws;                    // 2048*128              = 262144
    float* bufA= xn0 + 262144;          // 524288: h1, later h2+p3
    float* p2  = bufA + 524288;         // 2*2048*128            = 524288
    float* T1  = p2  + 524288;          // 128*6*256*2           = 393216
    float* K1  = T1  + 393216;          // 32768
    float* T2  = K1  + 32768;           // 256*6*128*2           = 393216
    float* K2  = T2  + 393216;          // 32768
    float* T3  = K2  + 32768;           // 128*6*64*2            = 98304
    float* K3  = T3  + 98304;           // 8192
    float* h1  = bufA;                  // [2048][256] (tanh'd)
    float* h2  = bufA;                  // [2048][128] (tanh'd), h1 dead by then
    float* p3  = bufA + 262144;         // [2][2048][64]

    prep_all<<<1312, 256, 0, stream>>>(x, xn0,
                                       w1, s1, T1, K1,
                                       w2, s2, T2, K2,
                                       w3, s3, T3, K3);

    // L1: IN=128, OUT=256, OCH=4, HALVES=1, BPT=4 -> 128 bb x 4 oc = 512 blocks
    kan_tile<128, 256, 4, 1, 4, 0><<<512, 256, 0, stream>>>(
        xn0, (const char*)T1, (const char*)K1, h1);
    // L2: 256 i's as 2 halves of 128; OUT=128, OCH=2 -> 128 x 2 x 2 = 512 blocks; raw partials
    kan_tile<128, 128, 2, 2, 4, 1><<<512, 256, 0, stream>>>(
        h1, (const char*)T2, (const char*)K2, p2);
    // combine halves -> tanh'd h2  (2048*128)
    combine_tanh<<<1024, 256, 0, stream>>>(p2, h2, 262144);
    // L3: 128 i's as 2 halves of 64; OUT=64, OCH=1 -> 128 x 1 x 2 = 256 blocks; raw partials
    kan_tile<64, 64, 1, 2, 4, 1><<<256, 256, 0, stream>>>(
        h2, (const char*)T3, (const char*)K3, p3);
    // epilogue: sigmoid(p0+p1) -> out  (2048*64)
    sigmoid_combine<<<512, 256, 0, stream>>>(p3, out, 131072);
}

// Round 13
// 107.117 us; speedup vs baseline: 1.7587x; 1.7587x over previous
//
#include <hip/hip_runtime.h>
#include <math.h>

#define GRID_N 5
#define LOG2E 1.4426950408889634f
#define EXP2F __builtin_amdgcn_exp2f
#define B 2048

__device__ __forceinline__ float tanh_fast(float v) {   // NaN-safe, saturating
    float e = EXP2F(2.0f * LOG2E * v);
    return 1.0f - 2.0f / (e + 1.0f);
}

// ---- table prep: record layout T[i][o][12] = {A1,B1,A2,B2,...,A5,B5,K,pad} (48B)
//   K = -s*log2e;  A[k] = sum_{g_idx<k} w_g*2^{-K*g},  B[k] = sum_{g_idx>=k} w_g*2^{K*g}
__device__ __forceinline__ void prep_one(const float* __restrict__ w,
                                         const float* __restrict__ s,
                                         float* __restrict__ T, int O, int I, int idx) {
    int o = idx / I, i = idx % I;               // w,s are [O][I(][G)]
    float K = -s[idx] * LOG2E;
    const float gv[5] = {-1.f, -0.5f, 0.f, 0.5f, 1.f};
    float A[6], Bb[6];
    A[0] = 0.f; Bb[5] = 0.f;
#pragma unroll
    for (int g = 0; g < 5; g++)
        A[g + 1] = A[g] + w[idx * GRID_N + g] * EXP2F(-K * gv[g]);
#pragma unroll
    for (int g = 4; g >= 0; g--)
        Bb[g] = Bb[g + 1] + w[idx * GRID_N + g] * EXP2F(K * gv[g]);
    float* r = T + ((size_t)i * O + o) * 12;
#pragma unroll
    for (int k = 1; k <= 5; k++) {
        r[2 * (k - 1)]     = A[k];
        r[2 * (k - 1) + 1] = Bb[k];
    }
    r[10] = K;
    r[11] = 0.f;
}

__global__ __launch_bounds__(256) void prep_tables(
    const float* __restrict__ w1, const float* __restrict__ s1, float* T1,
    const float* __restrict__ w2, const float* __restrict__ s2, float* T2,
    const float* __restrict__ w3, const float* __restrict__ s3, float* T3) {
    int idx = blockIdx.x * 256 + threadIdx.x;
    if (idx < 32768)       prep_one(w1, s1, T1, 256, 128, idx);
    else if (idx < 65536)  prep_one(w2, s2, T2, 128, 256, idx - 32768);
    else if (idx < 73728)  prep_one(w3, s3, T3,  64, 128, idx - 65536);
}

// x[2048][128] -> x0T[128][2048] with tanh, LDS-tiled 64x64
__global__ __launch_bounds__(256) void transpose_tanh(
    const float* __restrict__ x, float* __restrict__ xT) {
    __shared__ float lds[64][65];
    const int tx = threadIdx.x & 63, ty = threadIdx.x >> 6;
    const int b0 = (blockIdx.x & 31) << 6, i0 = (blockIdx.x >> 5) << 6;
#pragma unroll
    for (int rr = 0; rr < 16; rr++) {
        int r = rr * 4 + ty;
        lds[r][tx] = tanh_fast(x[(size_t)(b0 + r) * 128 + i0 + tx]);
    }
    __syncthreads();
#pragma unroll
    for (int rr = 0; rr < 16; rr++) {
        int r = rr * 4 + ty;
        xT[(size_t)(i0 + r) * B + b0 + tx] = lds[tx][r];
    }
}

// ---- lane=b KAN layer ----
// acc[b,o] = sum_i A[i,bin(b,i),o]*2^{K*xn(b,i)} + B[i,bin,o]*2^{-K*xn}
// Wave: 64 b's (lane=b), 4 o's (acc[4]), i in [h*LEN,(h+1)*LEN).
// xn lane-private (coalesced from xT[i][b]); bin -> koff VGPR once per (b,i),
// reused for 4 o's; table gather = uniform record base + koff: 64 lanes hit
// the same 48B record (1-2 lines). K at rec+40 is uniform -> s_load.
// Partials out to outp[NSPLIT][OUT][B] (coalesced).
template<int LEN, int OUT, int NSPLIT>
__global__ __launch_bounds__(256) void kan_g(
    const float* __restrict__ xnT,   // [IN_total][B], already tanh'd
    const char*  __restrict__ Tb,    // [IN_total][OUT][12] f32 records
    float* __restrict__ outp)        // [NSPLIT][OUT][B]
{
    constexpr int NOG = OUT / 4;
    const int lane = threadIdx.x & 63;
    const int widx = __builtin_amdgcn_readfirstlane(threadIdx.x >> 6);
    const int bq   = blockIdx.x & 7;
    const int og   = (blockIdx.x >> 3) % NOG;
    const int h    = (blockIdx.x >> 3) / NOG;
    const int bg   = bq * 4 + widx;
    const int gb   = (bg << 6) + lane;
    const int ibase = h * LEN;
    const int oabs  = og * 4;

    float acc[4] = {0.f, 0.f, 0.f, 0.f};

#pragma unroll 1
    for (int c = 0; c < LEN / 8; c++) {
        const int ic = ibase + c * 8;
        float xs[8];
        int   koff[8];
#pragma unroll
        for (int u = 0; u < 8; u++)
            xs[u] = xnT[(size_t)(ic + u) * B + gb];
#pragma unroll
        for (int u = 0; u < 8; u++) {
            int k = (int)(xs[u] * 2.0f + 2.0f);          // 0..4 (xs in [-1,1])
            koff[u] = (k > 4 ? 4 : k) << 3;              // (bin-1)*8 bytes
        }
#pragma unroll
        for (int u = 0; u < 8; u++) {
            const char* rec = Tb + ((size_t)(ic + u) * OUT + oabs) * 48;
#pragma unroll
            for (int o = 0; o < 4; o++) {
                float2 ab = *(const float2*)(rec + o * 48 + koff[u]);
                float  Kv = *(const float*)(rec + o * 48 + 40);
                float  t  = Kv * xs[u];
                acc[o] += ab.x * EXP2F(t) + ab.y * EXP2F(-t);
            }
        }
    }

#pragma unroll
    for (int o = 0; o < 4; o++)
        outp[((size_t)h * OUT + oabs + o) * B + gb] = acc[o];
}

// h[e] = tanh(relu(sum of NP partials))   (transposed elementwise)
template<int NP>
__global__ __launch_bounds__(256) void combine_tanh(
    const float* __restrict__ p, float* __restrict__ out, int n) {
    int e = blockIdx.x * 256 + threadIdx.x;
    if (e >= n) return;
    float z = p[e];
#pragma unroll
    for (int q = 1; q < NP; q++) z += p[(size_t)q * n + e];
    out[e] = tanh_fast(fmaxf(z, 0.f));
}

// out[b*64+o] = sigmoid(sum of 4 partials), e = o*B + b
__global__ __launch_bounds__(256) void sigmoid_combine_t(
    const float* __restrict__ p, float* __restrict__ out, int n) {
    int e = blockIdx.x * 256 + threadIdx.x;
    if (e >= n) return;
    float z = p[e] + p[n + e] + p[2 * n + e] + p[3 * n + e];
    int b = e & (B - 1), o = e >> 11;
    out[b * 64 + o] = 1.0f / (1.0f + EXP2F(-LOG2E * z));
}

extern "C" void kernel_launch(void* const* d_in, const int* in_sizes, int n_in,
                              void* d_out, int out_size, void* d_ws, size_t ws_size,
                              hipStream_t stream) {
    const float* x  = (const float*)d_in[0];
    const float* w1 = (const float*)d_in[1];
    const float* s1 = (const float*)d_in[2];
    const float* w2 = (const float*)d_in[3];
    const float* s2 = (const float*)d_in[4];
    const float* w3 = (const float*)d_in[5];
    const float* s3 = (const float*)d_in[6];
    float* out = (float*)d_out;

    float* ws  = (float*)d_ws;
    float* U   = ws;                    // 1048576: p1[2][256][B], later p2[4][128][B]
    float* V   = U + 1048576;           //  262144: x0T[128][B], later h2T[128][B]
    float* W   = V + 262144;            //  524288: h1T[256][B], later p3[4][64][B]
    float* T1  = W + 524288;            //  393216 = 128*256*12
    float* T2  = T1 + 393216;           //  393216 = 256*128*12
    float* T3  = T2 + 393216;           //   98304 = 128*64*12

    transpose_tanh<<<64, 256, 0, stream>>>(x, V);
    prep_tables<<<288, 256, 0, stream>>>(w1, s1, T1, w2, s2, T2, w3, s3, T3);

    // L1: IN=128 (2 halves of 64), OUT=256 -> 8 x 64 x 2 = 1024 blocks
    kan_g<64, 256, 2><<<1024, 256, 0, stream>>>(V, (const char*)T1, U);
    combine_tanh<2><<<2048, 256, 0, stream>>>(U, W, 524288);   // -> h1T[256][B]
    // L2: IN=256 (4 halves of 64), OUT=128 -> 8 x 32 x 4 = 1024 blocks
    kan_g<64, 128, 4><<<1024, 256, 0, stream>>>(W, (const char*)T2, U);
    combine_tanh<4><<<1024, 256, 0, stream>>>(U, V, 262144);   // -> h2T[128][B]
    // L3: IN=128 (4 quarters of 32), OUT=64 -> 8 x 16 x 4 = 512 blocks
    kan_g<32, 64, 4><<<512, 256, 0, stream>>>(V, (const char*)T3, W);
    sigmoid_combine_t<<<512, 256, 0, stream>>>(W, out, 131072);
}